// Round 3
// baseline (425.614 us; speedup 1.0000x reference)
//
#include <hip/hip_runtime.h>
#include <hip/hip_bf16.h>

using bf16 = __hip_bfloat16;

typedef __attribute__((ext_vector_type(8))) short short8;
typedef __attribute__((ext_vector_type(4))) float f32x4;

constexpr int Bb = 32, Dd = 256, HWw = 4096, Kk = 256, Ff = 2048;
constexpr float TEMP_INV = 1.0f / 0.07f;
constexpr float EPSf = 1e-6f;
constexpr float NORM_EPSf = 1e-12f;
constexpr float LN_EPSf = 1e-5f;

static __device__ __forceinline__ float b2f(bf16 v) { return __bfloat162float(v); }
static __device__ __forceinline__ bf16 f2b(float v) { return __float2bfloat16(v); }

// Fragment-order conventions (16x16x32 MFMA, K-step 32):
//   element (row, k): s' = k>>5, q2 = (k>>3)&3, j = k&7
//   256-row group (tnbf, attn_bf, xb_bf): fi = (row>>4)*64 + q2*16 + (row&15); 1024 frags/step
//   64-row group (tbf/w1bf/w2bf/h1bf):    fi = ((row&63)>>4)*64 + q2*16 + (row&15); 256 frags/step
// Reader identity: addr = set_base + (mtile_local*64 + lane)*8  (lane = q2*16 + row&15)
// LDS repack swizzle (bank-spread, involution): fi_sw = fi ^ ((fi>>3)&3)

// ---------------- k_tn: tnbf = l2norm(tgt) bf16, 256-row-group fragment order ----------------
__global__ __launch_bounds__(64) void k_tn(const float* __restrict__ tgt,
                                           bf16* __restrict__ tnbf) {
  int row = blockIdx.x;            // b*256 + slot
  int b = row >> 8, slot = row & 255;
  int lane = threadIdx.x;
  const float* src = tgt + (size_t)row * Dd + lane * 4;
  float v[4];
#pragma unroll
  for (int u = 0; u < 4; u++) v[u] = src[u];
  float ss = v[0] * v[0] + v[1] * v[1] + v[2] * v[2] + v[3] * v[3];
#pragma unroll
  for (int m = 32; m >= 1; m >>= 1) ss += __shfl_xor(ss, m, 64);
  float inv = 1.0f / fmaxf(sqrtf(ss), NORM_EPSf);
  bf16 o[4] __attribute__((aligned(8)));
#pragma unroll
  for (int u = 0; u < 4; u++) o[u] = f2b(v[u] * inv);
  int s = lane >> 3;
  int q2 = (lane >> 1) & 3;
  int jh = (lane & 1) * 4;
  size_t fi = (size_t)((slot >> 4) * 64 + q2 * 16 + (slot & 15));
  *(float2*)(tnbf + ((size_t)(b * 8 + s) * 1024 + fi) * 8 + jh) = *(float2*)o;
}

// ---------------- k_prew1: w1 (DFFxD fp32) -> 64-row-group fragment order bf16 ----------------
__global__ __launch_bounds__(64) void k_prew1(const float* __restrict__ w1,
                                              bf16* __restrict__ w1bf) {
  int f = blockIdx.x;              // 0..2047
  int lane = threadIdx.x;
  const float* src = w1 + (size_t)f * Dd + lane * 4;
  bf16 o[4] __attribute__((aligned(8)));
#pragma unroll
  for (int u = 0; u < 4; u++) o[u] = f2b(src[u]);
  int s = lane >> 3;
  int q2 = (lane >> 1) & 3;
  int jh = (lane & 1) * 4;
  size_t fi = (size_t)(((f & 63) >> 4) * 64 + q2 * 16 + (f & 15));
  *(float2*)(w1bf + ((size_t)((f >> 6) * 8 + s) * 256 + fi) * 8 + jh) = *(float2*)o;
}

// ---------------- k_prew2: w2 (DxDFF fp32) -> 64-row-group fragment order (64 f-steps) ----------------
__global__ __launch_bounds__(64) void k_prew2(const float* __restrict__ w2,
                                              bf16* __restrict__ w2bf) {
  int d = blockIdx.x;              // 0..255
  int lane = threadIdx.x;          // sg = lane (f-step)
  const float* src = w2 + (size_t)d * Ff + lane * 32;
  size_t gbase = (size_t)((d >> 6) * 64 + lane) * 256;
  int fbase = ((d & 63) >> 4) * 64 + (d & 15);
#pragma unroll
  for (int q2 = 0; q2 < 4; q2++) {
    float4 v0 = *(const float4*)(src + q2 * 8);
    float4 v1 = *(const float4*)(src + q2 * 8 + 4);
    bf16 o[8] __attribute__((aligned(16)));
    o[0] = f2b(v0.x); o[1] = f2b(v0.y); o[2] = f2b(v0.z); o[3] = f2b(v0.w);
    o[4] = f2b(v1.x); o[5] = f2b(v1.y); o[6] = f2b(v1.z); o[7] = f2b(v1.w);
    *(float4*)(w2bf + (gbase + fbase + q2 * 16) * 8) = *(float4*)o;
  }
}

#define MFMA16(a, b, c) __builtin_amdgcn_mfma_f32_16x16x32_bf16(a, b, c, 0, 0, 0)

// ---------------- k_dots: softmax(slots) -> attn_bf (frag order), xb_bf (frag order), S ----------------
// LDS layout (39936 B):
//   phase 1 (stage + K-loop):    Bs8  @ 0     (8 steps x 2080 bf16, 33280 B)
//                                ssred@ 33280 (64*17 f32,  4352 B)
//                                nxl  @ 37632 (64 f32,      256 B)
//                                red  @ 37888 (512 f32,    2048 B)   [red2 = red+256]
//   phase 2 (epilogue):          rp   @ 0     (8192 bf16, 16384 B)  attn repack tile (swizzled)
// Single staging barrier: all 8 K-steps staged to LDS up front (2 bursts of 8 float4 loads),
// then a barrier-free MFMA loop (lgkmcnt-only scheduling). Removes 7 of 8 barrier drains.
__global__ __launch_bounds__(256) void k_dots(const bf16* __restrict__ tnbf,
                                              const float* __restrict__ x,
                                              bf16* __restrict__ xb_bf,
                                              bf16* __restrict__ attn_bf,
                                              float* __restrict__ S) {
  __shared__ __align__(16) char smem[39936];
  bf16* Bs8 = (bf16*)smem;                   // [8][2080]
  float* ssred = (float*)(smem + 33280);     // [64*17]
  float* nxl = (float*)(smem + 37632);       // [64]
  float* red = (float*)(smem + 37888);       // [512]
  int b = blockIdx.x >> 6;
  int hw0 = (blockIdx.x & 63) * 64;
  int tid = threadIdx.x;
  int wave = tid >> 6, lane = tid & 63;
  int quad = lane >> 4, nl = lane & 15;

  int dp = tid >> 4;           // 0..15
  int ch = tid & 15;           // 0..15
  int qb = dp >> 2;
  int jb = (dp & 3) * 2;

  f32x4 acc[4][4];
#pragma unroll
  for (int i = 0; i < 4; i++)
#pragma unroll
    for (int j = 0; j < 4; j++) acc[i][j] = (f32x4){0.f, 0.f, 0.f, 0.f};
  float ssp[4] = {0.f, 0.f, 0.f, 0.f};

  // xb_bf write coords for this thread (per step s, rows d=s*32+2dp, +1)
  int spx = (hw0 >> 5) + (ch >> 3);       // s' local to b
  int q2x = (ch >> 1) & 3;
  int jx = (ch & 1) * 4;

  // ---- stage ALL 8 K-steps into LDS (two 4-step bursts), xb_bf stores along the way ----
#pragma unroll 1
  for (int c = 0; c < 2; c++) {
    float4 va4[4], vb4[4];
#pragma unroll
    for (int q = 0; q < 4; q++) {
      const float* xr = x + (size_t)((b << 8) + (c * 4 + q) * 32 + 2 * dp) * HWw + hw0 + ch * 4;
      va4[q] = *(const float4*)xr;
      vb4[q] = *(const float4*)(xr + HWw);
    }
#pragma unroll
    for (int q = 0; q < 4; q++) {
      int s = c * 4 + q;
      float vva[4] = {va4[q].x, va4[q].y, va4[q].z, va4[q].w};
      float vvb[4] = {vb4[q].x, vb4[q].y, vb4[q].z, vb4[q].w};
      bf16 pa[4] __attribute__((aligned(8)));
      bf16 pb[4] __attribute__((aligned(8)));
#pragma unroll
      for (int jj = 0; jj < 4; jj++) {
        ssp[jj] += vva[jj] * vva[jj] + vvb[jj] * vvb[jj];
        pa[jj] = f2b(vva[jj]);
        pb[jj] = f2b(vvb[jj]);
      }
      // xb_bf fragment-order store (8B each, two adjacent d-rows)
      int d0r = s * 32 + 2 * dp;
      int fiA = (d0r >> 4) * 64 + q2x * 16 + (d0r & 15);
      size_t base = ((size_t)(b * 128) + spx) * 1024;
      *(float2*)(xb_bf + (base + fiA) * 8 + jx) = *(float2*)pa;
      *(float2*)(xb_bf + (base + fiA + 1) * 8 + jx) = *(float2*)pb;
      // LDS stage for step s
#pragma unroll
      for (int jj = 0; jj < 4; jj++) {
        int hwl = ch * 4 + jj;
        int nt = hwl >> 4;
        int li = (qb << 4) | (hwl & 15);
        union { bf16 h[2]; unsigned int u; } pk;
        pk.h[0] = pa[jj];
        pk.h[1] = pb[jj];
        *(unsigned int*)&Bs8[s * 2080 + nt * 520 + li * 8 + jb] = pk.u;
      }
    }
  }
  __syncthreads();   // the ONE staging drain

  // ---- barrier-free MFMA loop over 8 staged K-steps, 1-ahead tnbf prefetch ----
  short8 afp[4];
  {
    const bf16* ts0 = tnbf + (size_t)(b * 8) * 1024 * 8;
#pragma unroll
    for (int mt = 0; mt < 4; mt++)
      afp[mt] = *(const short8*)(ts0 + (size_t)(((wave << 2) + mt) * 64 + lane) * 8);
  }
  for (int s = 0; s < 8; s++) {
    short8 af[4];
#pragma unroll
    for (int mt = 0; mt < 4; mt++) af[mt] = afp[mt];
    if (s < 7) {
      const bf16* tsrc = tnbf + (size_t)(b * 8 + s + 1) * 1024 * 8;
#pragma unroll
      for (int mt = 0; mt < 4; mt++)
        afp[mt] = *(const short8*)(tsrc + (size_t)(((wave << 2) + mt) * 64 + lane) * 8);
    }
    short8 bfv[4];
#pragma unroll
    for (int nt = 0; nt < 4; nt++)
      bfv[nt] = *(const short8*)(Bs8 + s * 2080 + nt * 520 + lane * 8);
#pragma unroll
    for (int mt = 0; mt < 4; mt++)
#pragma unroll
      for (int nt = 0; nt < 4; nt++) acc[mt][nt] = MFMA16(af[mt], bfv[nt], acc[mt][nt]);
  }

#pragma unroll
  for (int jj = 0; jj < 4; jj++) ssred[(ch * 4 + jj) * 17 + dp] = ssp[jj];
  __syncthreads();
  if (tid < 64) {
    float sum = 0.f;
#pragma unroll
    for (int i = 0; i < 16; i++) sum += ssred[tid * 17 + i];
    nxl[tid] = TEMP_INV / fmaxf(sqrtf(sum), NORM_EPSf);
  }
  __syncthreads();

  float sc[4];
#pragma unroll
  for (int nt = 0; nt < 4; nt++) sc[nt] = nxl[nt * 16 + nl];
#pragma unroll
  for (int mt = 0; mt < 4; mt++)
#pragma unroll
    for (int nt = 0; nt < 4; nt++)
#pragma unroll
      for (int r = 0; r < 4; r++) acc[mt][nt][r] *= sc[nt];

  float* red2 = red + 256;

  float pmax[4];
#pragma unroll
  for (int nt = 0; nt < 4; nt++) {
    float m = acc[0][nt][0];
#pragma unroll
    for (int mt = 0; mt < 4; mt++)
#pragma unroll
      for (int r = 0; r < 4; r++) m = fmaxf(m, acc[mt][nt][r]);
    m = fmaxf(m, __shfl_xor(m, 16, 64));
    m = fmaxf(m, __shfl_xor(m, 32, 64));
    pmax[nt] = m;
  }
  if (lane < 16) {
#pragma unroll
    for (int nt = 0; nt < 4; nt++) red[((wave << 2) + nt) * 16 + nl] = pmax[nt];
  }
  __syncthreads();
  float cmax[4];
#pragma unroll
  for (int nt = 0; nt < 4; nt++) {
    float m = red[nt * 16 + nl];
#pragma unroll
    for (int w2 = 1; w2 < 4; w2++) m = fmaxf(m, red[((w2 << 2) + nt) * 16 + nl]);
    cmax[nt] = m;
  }

  float psum[4];
#pragma unroll
  for (int nt = 0; nt < 4; nt++) {
    float s = 0.f;
#pragma unroll
    for (int mt = 0; mt < 4; mt++)
#pragma unroll
      for (int r = 0; r < 4; r++) {
        float e = __expf(acc[mt][nt][r] - cmax[nt]);
        acc[mt][nt][r] = e;
        s += e;
      }
    s += __shfl_xor(s, 16, 64);
    s += __shfl_xor(s, 32, 64);
    psum[nt] = s;
  }
  if (lane < 16) {
#pragma unroll
    for (int nt = 0; nt < 4; nt++) red2[((wave << 2) + nt) * 16 + nl] = psum[nt];
  }
  __syncthreads();
  float ci[4];
#pragma unroll
  for (int nt = 0; nt < 4; nt++) {
    float s = 0.f;
#pragma unroll
    for (int w2 = 0; w2 < 4; w2++) s += red2[((w2 << 2) + nt) * 16 + nl];
    ci[nt] = 1.0f / s;
  }

  // ---- quantize + spatial sums S (values kept in acc as exact bf16 round-trips) ----
#pragma unroll
  for (int mt = 0; mt < 4; mt++) {
    int slotg = (b << 8) + (wave << 6) + (mt << 4) + (quad << 2);
#pragma unroll
    for (int r = 0; r < 4; r++) {
      float rs = 0.f;
#pragma unroll
      for (int nt = 0; nt < 4; nt++) {
        bf16 hb = f2b(acc[mt][nt][r] * ci[nt] + EPSf);
        float q = b2f(hb);
        acc[mt][nt][r] = q;
        rs += q;
      }
      rs += __shfl_xor(rs, 1, 64);
      rs += __shfl_xor(rs, 2, 64);
      rs += __shfl_xor(rs, 4, 64);
      rs += __shfl_xor(rs, 8, 64);
      if (nl == 0) atomicAdd(&S[slotg + r], rs);
    }
  }

  // ---- attn epilogue: repack through LDS (swizzled), flush with coalesced 16B stores ----
  __syncthreads();                 // all waves past MFMA loop + red2 reads; smem reusable
  bf16* rp = (bf16*)smem;          // [1024 frags][8] bf16 = 16 KB (one s' half)
  int jat = nl & 7;
#pragma unroll
  for (int h = 0; h < 2; h++) {    // h = s'-half (nt 0,1 then nt 2,3)
#pragma unroll
    for (int mt = 0; mt < 4; mt++) {
      int fi0 = ((wave << 2) + mt) * 64 + (quad << 2);
#pragma unroll
      for (int ntl = 0; ntl < 2; ntl++) {
        int nt = (h << 1) + ntl;
        int q2p = (ntl << 1) + (nl >> 3);
#pragma unroll
        for (int r = 0; r < 4; r++) {
          int fi = fi0 + q2p * 16 + r;
          int fisw = fi ^ ((fi >> 3) & 3);       // bank-spread swizzle (involution)
          rp[fisw * 8 + jat] = f2b(acc[mt][nt][r]);
        }
      }
    }
    __syncthreads();
    size_t gbase = ((size_t)(b * 128) + (hw0 >> 5) + h) * 1024 * 8;
#pragma unroll
    for (int u = 0; u < 4; u++) {
      int fl = u * 256 + tid;
      int fg = fl ^ ((fl >> 3) & 3);             // inverse (same) swizzle
      short8 vv = *(const short8*)(rp + (size_t)fl * 8);
      *(short8*)(attn_bf + gbase + (size_t)fg * 8) = vv;
    }
    if (h == 0) __syncthreads();   // flush reads done before overwriting rp
  }
}

// ---------------- GEMM2 (MFMA, zero-LDS, full-K, direct t2 write, NO partials) ----------------
// grid 512: b(32) x kp(4) x dgrp(4). b = n&31 -> all 16 blocks/batch on XCD b%8.
__global__ __launch_bounds__(256) void k_gemm2(const bf16* __restrict__ attn_bf,
                                               const bf16* __restrict__ xb_bf,
                                               float* __restrict__ t2) {
  int n = blockIdx.x;
  int b = n & 31;
  int r2 = n >> 5;                 // 0..15
  int kp = r2 & 3;                 // 64-slot tile
  int dgrp = r2 >> 2;              // 64-d tile
  int tid = threadIdx.x;
  int wave = tid >> 6, lane = tid & 63;
  int wr = wave >> 1, wc = wave & 1;

  f32x4 acc[2][2];
#pragma unroll
  for (int i = 0; i < 2; i++)
#pragma unroll
    for (int j = 0; j < 2; j++) acc[i][j] = (f32x4){0.f, 0.f, 0.f, 0.f};

  const bf16* Abase = attn_bf + ((size_t)(b * 128) * 1024 + (size_t)(kp * 4 + wr * 2) * 64) * 8;
  const bf16* Bbase = xb_bf + ((size_t)(b * 128) * 1024 + (size_t)(dgrp * 4 + wc * 2) * 64) * 8;
#pragma unroll 4
  for (int st = 0; st < 128; st++) {
    const bf16* Ap = Abase + (size_t)st * 1024 * 8;
    const bf16* Bp = Bbase + (size_t)st * 1024 * 8;
    short8 a0 = *(const short8*)(Ap + (size_t)lane * 8);
    short8 a1 = *(const short8*)(Ap + (size_t)(64 + lane) * 8);
    short8 b0 = *(const short8*)(Bp + (size_t)lane * 8);
    short8 b1 = *(const short8*)(Bp + (size_t)(64 + lane) * 8);
    acc[0][0] = MFMA16(a0, b0, acc[0][0]);
    acc[0][1] = MFMA16(a0, b1, acc[0][1]);
    acc[1][0] = MFMA16(a1, b0, acc[1][0]);
    acc[1][1] = MFMA16(a1, b1, acc[1][1]);
  }
  int quad = lane >> 4, nl = lane & 15;
#pragma unroll
  for (int i = 0; i < 2; i++)
#pragma unroll
    for (int r = 0; r < 4; r++) {
      int row = (b << 8) + kp * 64 + wr * 32 + i * 16 + quad * 4 + r;
#pragma unroll
      for (int j = 0; j < 2; j++) {
        int col = dgrp * 64 + wc * 32 + j * 16 + nl;
        t2[(size_t)row * Dd + col] = acc[i][j][r];
      }
    }
}

// ---------------- LN_pre: t = LN(t2/S + tgt); also tbf (64-row-group frag order) ----------------
__global__ __launch_bounds__(64) void k_ln_pre(const float* __restrict__ t2,
                                               const float* __restrict__ S,
                                               const float* __restrict__ tgt,
                                               const float* __restrict__ g,
                                               const float* __restrict__ be,
                                               float* __restrict__ t,
                                               bf16* __restrict__ tbf) {
  int row = blockIdx.x;
  int lane = threadIdx.x;
  float sInv = 1.0f / S[row];
  size_t off = (size_t)row * Dd + lane * 4;
  float4 a0 = *(const float4*)(t2 + off);
  const float* pt = tgt + off;
  float v[4];
  v[0] = a0.x * sInv + pt[0];
  v[1] = a0.y * sInv + pt[1];
  v[2] = a0.z * sInv + pt[2];
  v[3] = a0.w * sInv + pt[3];
  float s1 = v[0] + v[1] + v[2] + v[3];
  float s2 = v[0] * v[0] + v[1] * v[1] + v[2] * v[2] + v[3] * v[3];
#pragma unroll
  for (int m = 32; m >= 1; m >>= 1) {
    s1 += __shfl_xor(s1, m, 64);
    s2 += __shfl_xor(s2, m, 64);
  }
  float mu = s1 * (1.0f / 256.0f);
  float var = s2 * (1.0f / 256.0f) - mu * mu;
  float rs = rsqrtf(fmaxf(var, 0.f) + LN_EPSf);
  float* po = t + (size_t)row * Dd + lane * 4;
  bf16 o[4] __attribute__((aligned(8)));
#pragma unroll
  for (int u = 0; u < 4; u++) {
    float val = (v[u] - mu) * rs * g[lane * 4 + u] + be[lane * 4 + u];
    po[u] = val;
    o[u] = f2b(val);
  }
  int s = lane >> 3;
  int q2 = (lane >> 1) & 3;
  int jh = (lane & 1) * 4;
  size_t fi = (size_t)(((row & 63) >> 4) * 64 + q2 * 16 + (row & 15));
  *(float2*)(tbf + ((size_t)((row >> 6) * 8 + s) * 256 + fi) * 8 + jh) = *(float2*)o;
}

// ---------------- FFN GEMM3 (MFMA): h1bf = relu(tbf @ w1bf^T + b1), frag order via LDS repack ----------------
__global__ __launch_bounds__(256) void k_ffn1(const bf16* __restrict__ tbf,
                                              const bf16* __restrict__ w1bf,
                                              const float* __restrict__ b1,
                                              bf16* __restrict__ h1bf) {
  __shared__ __align__(16) bf16 rp[512 * 8];   // 8 KB: 2 frag-sets x 256 frags x 8
  int rowgrp = blockIdx.x >> 5;    // 0..127
  int fgrp = blockIdx.x & 31;      // 0..31
  int tid = threadIdx.x;
  int wave = tid >> 6, lane = tid & 63;
  int am = (wave >> 1) * 2, bn = (wave & 1) * 2;

  f32x4 acc[2][2];
#pragma unroll
  for (int i = 0; i < 2; i++)
#pragma unroll
    for (int j = 0; j < 2; j++) acc[i][j] = (f32x4){0.f, 0.f, 0.f, 0.f};

  const bf16* Abase = tbf + (size_t)rowgrp * 8 * 256 * 8;
  const bf16* Bbase = w1bf + (size_t)fgrp * 8 * 256 * 8;
#pragma unroll
  for (int s = 0; s < 8; s++) {
    short8 af[2], bfr[2];
#pragma unroll
    for (int i = 0; i < 2; i++)
      af[i] = *(const short8*)(Abase + ((size_t)s * 256 + ((am + i) * 64 + lane)) * 8);
#pragma unroll
    for (int j = 0; j < 2; j++)
      bfr[j] = *(const short8*)(Bbase + ((size_t)s * 256 + ((bn + j) * 64 + lane)) * 8);
#pragma unroll
    for (int i = 0; i < 2; i++)
#pragma unroll
      for (int j = 0; j < 2; j++) acc[i][j] = MFMA16(af[i], bfr[j], acc[i][j]);
  }
  int quad = lane >> 4, nl = lane & 15;
  int jat = nl & 7;
#pragma unroll
  for (int j = 0; j < 2; j++) {
    int f = fgrp * 64 + (bn + j) * 16 + nl;
    float bias = b1[f];
    int seth = (bn + j) >> 1;                    // frag-set (32-f half) 0/1
    int q2p = ((bn + j) & 1) * 2 + (nl >> 3);
#pragma unroll
    for (int i = 0; i < 2; i++) {
      int fiBase = (am + i) * 64 + q2p * 16 + (quad << 2);
#pragma unroll
      for (int r = 0; r < 4; r++) {
        float val = fmaxf(acc[i][j][r] + bias, 0.f);
        int fi = fiBase + r;
        int fisw = fi ^ ((fi >> 3) & 3);         // bank-spread swizzle
        rp[(seth * 256 + fisw) * 8 + jat] = f2b(val);
      }
    }
  }
  __syncthreads();
  size_t sp0 = (size_t)(rowgrp * 64) + fgrp * 2;
#pragma unroll
  for (int u = 0; u < 2; u++) {
    int loc = tid;                               // frag within set
    int fg = loc ^ ((loc >> 3) & 3);             // inverse swizzle
    short8 vv = *(const short8*)(rp + ((size_t)u * 256 + loc) * 8);
    *(short8*)(h1bf + ((sp0 + u) * 256 + fg) * 8) = vv;
  }
}

// ---------------- FFN GEMM4 (MFMA, full-K, waves split K, LDS reduce, direct o2 write) ----------------
// grid 512: rowgrp(128) x cg(4). Wave w covers K-steps [w*16, w*16+16); end cross-wave reduce.
__global__ __launch_bounds__(256) void k_ffn2(const bf16* __restrict__ h1bf,
                                              const bf16* __restrict__ w2bf,
                                              float* __restrict__ o2) {
  __shared__ float redsm[4 * 4160];              // 4 waves x (64 rows x 65 pitch) = 66.5 KB
  int n = blockIdx.x;
  int rowgrp = n >> 2;             // 0..127
  int cg = n & 3;                  // 0..3 (64-col group)
  int tid = threadIdx.x;
  int wave = tid >> 6, lane = tid & 63;

  f32x4 acc[4][4];
#pragma unroll
  for (int i = 0; i < 4; i++)
#pragma unroll
    for (int j = 0; j < 4; j++) acc[i][j] = (f32x4){0.f, 0.f, 0.f, 0.f};

#pragma unroll 4
  for (int stl = 0; stl < 16; stl++) {
    int sg = wave * 16 + stl;
    const bf16* Ab = h1bf + ((size_t)(rowgrp * 64 + sg) * 256) * 8;
    const bf16* Bbv = w2bf + ((size_t)(cg * 64 + sg) * 256) * 8;
    short8 af[4], bfr[4];
#pragma unroll
    for (int mt = 0; mt < 4; mt++)
      af[mt] = *(const short8*)(Ab + (size_t)(mt * 64 + lane) * 8);
#pragma unroll
    for (int nt = 0; nt < 4; nt++)
      bfr[nt] = *(const short8*)(Bbv + (size_t)(nt * 64 + lane) * 8);
#pragma unroll
    for (int mt = 0; mt < 4; mt++)
#pragma unroll
      for (int nt = 0; nt < 4; nt++) acc[mt][nt] = MFMA16(af[mt], bfr[nt], acc[mt][nt]);
  }
  int quad = lane >> 4, nl = lane & 15;
  float* my = redsm + wave * 4160;
#pragma unroll
  for (int mt = 0; mt < 4; mt++)
#pragma unroll
    for (int r = 0; r < 4; r++) {
      int row = mt * 16 + quad * 4 + r;
#pragma unroll
      for (int nt = 0; nt < 4; nt++)
        my[row * 65 + nt * 16 + nl] = acc[mt][nt][r];
    }
  __syncthreads();
#pragma unroll
  for (int u = 0; u < 16; u++) {
    int o = u * 256 + tid;
    int row = o >> 6, col = o & 63;
    int li = row * 65 + col;
    float ssum = redsm[li] + redsm[4160 + li] + redsm[8320 + li] + redsm[12480 + li];
    o2[(size_t)(rowgrp * 64 + row) * Dd + cg * 64 + col] = ssum;
  }
}

// ---------------- LN_out: out = LN(o2 + b2 + t) with g3/be3 ----------------
__global__ __launch_bounds__(64) void k_ln_out(const float* __restrict__ o2,
                                               const float* __restrict__ b2v,
                                               const float* __restrict__ t,
                                               const float* __restrict__ g,
                                               const float* __restrict__ be,
                                               float* __restrict__ out) {
  int row = blockIdx.x;
  int lane = threadIdx.x;
  size_t off = (size_t)row * Dd + lane * 4;
  float4 aq = *(const float4*)(o2 + off);
  const float* pt = t + off;
  float v[4];
  v[0] = aq.x + b2v[lane * 4 + 0] + pt[0];
  v[1] = aq.y + b2v[lane * 4 + 1] + pt[1];
  v[2] = aq.z + b2v[lane * 4 + 2] + pt[2];
  v[3] = aq.w + b2v[lane * 4 + 3] + pt[3];
  float s1 = v[0] + v[1] + v[2] + v[3];
  float s2 = v[0] * v[0] + v[1] * v[1] + v[2] * v[2] + v[3] * v[3];
#pragma unroll
  for (int m = 32; m >= 1; m >>= 1) {
    s1 += __shfl_xor(s1, m, 64);
    s2 += __shfl_xor(s2, m, 64);
  }
  float mu = s1 * (1.0f / 256.0f);
  float var = s2 * (1.0f / 256.0f) - mu * mu;
  float rs = rsqrtf(fmaxf(var, 0.f) + LN_EPSf);
  float* pw = out + (size_t)row * Dd + lane * 4;
#pragma unroll
  for (int u = 0; u < 4; u++)
    pw[u] = (v[u] - mu) * rs * g[lane * 4 + u] + be[lane * 4 + u];
}

extern "C" void kernel_launch(void* const* d_in, const int* in_sizes, int n_in,
                              void* d_out, int out_size, void* d_ws, size_t ws_size,
                              hipStream_t stream) {
  const float* x = (const float*)d_in[0];
  const float* tgt = (const float*)d_in[1];
  const float* w1 = (const float*)d_in[2];
  const float* b1 = (const float*)d_in[3];
  const float* w2 = (const float*)d_in[4];
  const float* b2v = (const float*)d_in[5];
  const float* g2 = (const float*)d_in[6];
  const float* be2 = (const float*)d_in[7];
  const float* g3 = (const float*)d_in[8];
  const float* be3 = (const float*)d_in[9];
  float* out = (float*)d_out;

  // Aliasing:
  //   tbf -> tnbf (dead after k_dots)
  //   w1bf/w2bf carved from attn_bf head (attn dead after gemm2; prew runs after gemm2)
  //   t2 (8MB, single) -> h1bf region (h1bf written later by ffn1; t2 read by ln_pre first)
  //   o2 (8MB, single) -> xb_bf region (xb dead after gemm2)
  char* w = (char*)d_ws;
  bf16* tnbf = (bf16*)w;     w += (size_t)Bb * Kk * Dd * 2;   // 4 MB
  float* S = (float*)w;      w += (size_t)Bb * Kk * 4;        // 32 KB
  float* t = (float*)w;      w += (size_t)Bb * Kk * Dd * 4;   // 8 MB
  bf16* attn_bf = (bf16*)w;  w += (size_t)Bb * HWw * Kk * 2;  // 64 MB
  bf16* h1bf = (bf16*)w;     w += (size_t)Bb * Kk * Ff * 2;   // 32 MB
  bf16* xb_bf = (bf16*)w;    w += (size_t)Bb * Dd * HWw * 2;  // 64 MB

  bf16* tbf = tnbf;                        // 4 MB alias
  bf16* w1bf = attn_bf;                    // 1 MB carve
  bf16* w2bf = attn_bf + (size_t)Ff * Dd;  // 1 MB carve
  float* t2 = (float*)h1bf;                // 8 MB alias
  float* o2 = (float*)xb_bf;               // 8 MB alias

  hipMemsetAsync(S, 0, (size_t)Bb * Kk * 4, stream);
  k_tn<<<Bb * Kk, 64, 0, stream>>>(tgt, tnbf);
  k_dots<<<Bb * (HWw / 64), 256, 0, stream>>>(tnbf, x, xb_bf, attn_bf, S);
  k_gemm2<<<512, 256, 0, stream>>>(attn_bf, xb_bf, t2);
  k_prew1<<<Ff, 64, 0, stream>>>(w1, w1bf);
  k_prew2<<<Dd, 64, 0, stream>>>(w2, w2bf);
  k_ln_pre<<<Bb * Kk, 64, 0, stream>>>(t2, S, tgt, g2, be2, t, tbf);
  k_ffn1<<<(Bb * Kk / 64) * (Ff / 64), 256, 0, stream>>>(tbf, w1bf, b1, h1bf);
  k_ffn2<<<512, 256, 0, stream>>>(h1bf, w2bf, o2);
  k_ln_out<<<Bb * Kk, 64, 0, stream>>>(o2, b2v, t, g3, be3, out);
}

// Round 4
// 391.089 us; speedup vs baseline: 1.0883x; 1.0883x over previous
//
#include <hip/hip_runtime.h>
#include <hip/hip_bf16.h>

using bf16 = __hip_bfloat16;

typedef __attribute__((ext_vector_type(8))) short short8;
typedef __attribute__((ext_vector_type(4))) float f32x4;

constexpr int Bb = 32, Dd = 256, HWw = 4096, Kk = 256, Ff = 2048;
constexpr float TEMP_INV = 1.0f / 0.07f;
constexpr float EPSf = 1e-6f;
constexpr float NORM_EPSf = 1e-12f;
constexpr float LN_EPSf = 1e-5f;

static __device__ __forceinline__ float b2f(bf16 v) { return __bfloat162float(v); }
static __device__ __forceinline__ bf16 f2b(float v) { return __float2bfloat16(v); }

// Fragment-order conventions (16x16x32 MFMA, K-step 32):
//   element (row, k): s' = k>>5, q2 = (k>>3)&3, j = k&7
//   256-row group (tnbf, attn_bf, xb_bf): fi = (row>>4)*64 + q2*16 + (row&15); 1024 frags/step
//   64-row group (tbf/w1bf/w2bf/h1bf):    fi = ((row&63)>>4)*64 + q2*16 + (row&15); 256 frags/step
// Reader identity: addr = set_base + (mtile_local*64 + lane)*8  (lane = q2*16 + row&15)
// LDS repack swizzle (bank-spread, involution): fi_sw = fi ^ ((fi>>3)&3)

// ---------------- k_tn: tnbf = l2norm(tgt) bf16, 256-row-group fragment order ----------------
__global__ __launch_bounds__(64) void k_tn(const float* __restrict__ tgt,
                                           bf16* __restrict__ tnbf) {
  int row = blockIdx.x;            // b*256 + slot
  int b = row >> 8, slot = row & 255;
  int lane = threadIdx.x;
  const float* src = tgt + (size_t)row * Dd + lane * 4;
  float v[4];
#pragma unroll
  for (int u = 0; u < 4; u++) v[u] = src[u];
  float ss = v[0] * v[0] + v[1] * v[1] + v[2] * v[2] + v[3] * v[3];
#pragma unroll
  for (int m = 32; m >= 1; m >>= 1) ss += __shfl_xor(ss, m, 64);
  float inv = 1.0f / fmaxf(sqrtf(ss), NORM_EPSf);
  bf16 o[4] __attribute__((aligned(8)));
#pragma unroll
  for (int u = 0; u < 4; u++) o[u] = f2b(v[u] * inv);
  int s = lane >> 3;
  int q2 = (lane >> 1) & 3;
  int jh = (lane & 1) * 4;
  size_t fi = (size_t)((slot >> 4) * 64 + q2 * 16 + (slot & 15));
  *(float2*)(tnbf + ((size_t)(b * 8 + s) * 1024 + fi) * 8 + jh) = *(float2*)o;
}

// ---------------- k_prew1: w1 (DFFxD fp32) -> 64-row-group fragment order bf16 ----------------
__global__ __launch_bounds__(64) void k_prew1(const float* __restrict__ w1,
                                              bf16* __restrict__ w1bf) {
  int f = blockIdx.x;              // 0..2047
  int lane = threadIdx.x;
  const float* src = w1 + (size_t)f * Dd + lane * 4;
  bf16 o[4] __attribute__((aligned(8)));
#pragma unroll
  for (int u = 0; u < 4; u++) o[u] = f2b(src[u]);
  int s = lane >> 3;
  int q2 = (lane >> 1) & 3;
  int jh = (lane & 1) * 4;
  size_t fi = (size_t)(((f & 63) >> 4) * 64 + q2 * 16 + (f & 15));
  *(float2*)(w1bf + ((size_t)((f >> 6) * 8 + s) * 256 + fi) * 8 + jh) = *(float2*)o;
}

// ---------------- k_prew2: w2 (DxDFF fp32) -> 64-row-group fragment order (64 f-steps) ----------------
__global__ __launch_bounds__(64) void k_prew2(const float* __restrict__ w2,
                                              bf16* __restrict__ w2bf) {
  int d = blockIdx.x;              // 0..255
  int lane = threadIdx.x;          // sg = lane (f-step)
  const float* src = w2 + (size_t)d * Ff + lane * 32;
  size_t gbase = (size_t)((d >> 6) * 64 + lane) * 256;
  int fbase = ((d & 63) >> 4) * 64 + (d & 15);
#pragma unroll
  for (int q2 = 0; q2 < 4; q2++) {
    float4 v0 = *(const float4*)(src + q2 * 8);
    float4 v1 = *(const float4*)(src + q2 * 8 + 4);
    bf16 o[8] __attribute__((aligned(16)));
    o[0] = f2b(v0.x); o[1] = f2b(v0.y); o[2] = f2b(v0.z); o[3] = f2b(v0.w);
    o[4] = f2b(v1.x); o[5] = f2b(v1.y); o[6] = f2b(v1.z); o[7] = f2b(v1.w);
    *(float4*)(w2bf + (gbase + fbase + q2 * 16) * 8) = *(float4*)o;
  }
}

#define MFMA16(a, b, c) __builtin_amdgcn_mfma_f32_16x16x32_bf16(a, b, c, 0, 0, 0)

// ---------------- k_dots: softmax(slots) -> attn_bf (frag order), xb_bf (frag order), S ----------------
// Pair-wise double-buffered pipeline: K-steps processed in pairs (2 steps / barrier).
// Loads for pair p+1 issue right after pair p's barrier and fly under 32 MFMAs.
// xb stores issue after the barrier, drain at the NEXT barrier (one full pair later).
// LDS layout (23296 B):
//   phase 1:  Bs   @ 0     (4 step-slots x 2080 bf16, 16640 B; pair p uses slots 2(p&1)..)
//             ssred@ 16640 (64*17 f32, 4352 B)
//             nxl  @ 20992 (64 f32, 256 B)
//             red  @ 21248 (512 f32, 2048 B)   [red2 = red+256]
//   phase 2:  rp   @ 0     (8192 bf16, 16384 B) attn repack tile (swizzled), aliases Bs
__global__ __launch_bounds__(256) void k_dots(const bf16* __restrict__ tnbf,
                                              const float* __restrict__ x,
                                              bf16* __restrict__ xb_bf,
                                              bf16* __restrict__ attn_bf,
                                              float* __restrict__ S) {
  __shared__ __align__(16) char smem[23296];
  bf16* Bs = (bf16*)smem;                    // [4][2080]
  float* ssred = (float*)(smem + 16640);     // [64*17]
  float* nxl = (float*)(smem + 20992);       // [64]
  float* red = (float*)(smem + 21248);       // [512]
  int b = blockIdx.x >> 6;
  int hw0 = (blockIdx.x & 63) * 64;
  int tid = threadIdx.x;
  int wave = tid >> 6, lane = tid & 63;
  int quad = lane >> 4, nl = lane & 15;

  int dp = tid >> 4;           // 0..15
  int ch = tid & 15;           // 0..15
  int qb = dp >> 2;
  int jb = (dp & 3) * 2;

  f32x4 acc[4][4];
#pragma unroll
  for (int i = 0; i < 4; i++)
#pragma unroll
    for (int j = 0; j < 4; j++) acc[i][j] = (f32x4){0.f, 0.f, 0.f, 0.f};
  float ssp[4] = {0.f, 0.f, 0.f, 0.f};

  // xb_bf write coords for this thread (per step s, rows d=s*32+2dp, +1)
  int spx = (hw0 >> 5) + (ch >> 3);       // s' local to b
  int q2x = (ch >> 1) & 3;
  int jx = (ch & 1) * 4;

  // ---- prologue: load pair 0 (steps 0,1) + tnbf A-frags for s=0 ----
  float4 va4[2], vb4[2];
#pragma unroll
  for (int q = 0; q < 2; q++) {
    const float* xr = x + (size_t)((b << 8) + q * 32 + 2 * dp) * HWw + hw0 + ch * 4;
    va4[q] = *(const float4*)xr;
    vb4[q] = *(const float4*)(xr + HWw);
  }
  short8 afp[4];
  {
    const bf16* ts0 = tnbf + (size_t)(b * 8) * 1024 * 8;
#pragma unroll
    for (int mt = 0; mt < 4; mt++)
      afp[mt] = *(const short8*)(ts0 + (size_t)(((wave << 2) + mt) * 64 + lane) * 8);
  }

#pragma unroll 1
  for (int p = 0; p < 4; p++) {
    bf16* bsb = Bs + (p & 1) * 2 * 2080;
    bf16 paS[2][4] __attribute__((aligned(8)));
    bf16 pbS[2][4] __attribute__((aligned(8)));
    // convert + LDS-store pair p
#pragma unroll
    for (int q = 0; q < 2; q++) {
      float vva[4] = {va4[q].x, va4[q].y, va4[q].z, va4[q].w};
      float vvb[4] = {vb4[q].x, vb4[q].y, vb4[q].z, vb4[q].w};
#pragma unroll
      for (int jj = 0; jj < 4; jj++) {
        ssp[jj] += vva[jj] * vva[jj] + vvb[jj] * vvb[jj];
        paS[q][jj] = f2b(vva[jj]);
        pbS[q][jj] = f2b(vvb[jj]);
      }
#pragma unroll
      for (int jj = 0; jj < 4; jj++) {
        int hwl = ch * 4 + jj;
        int nt = hwl >> 4;
        int li = (qb << 4) | (hwl & 15);
        union { bf16 h[2]; unsigned int u; } pk;
        pk.h[0] = paS[q][jj];
        pk.h[1] = pbS[q][jj];
        *(unsigned int*)&bsb[q * 2080 + nt * 520 + li * 8 + jb] = pk.u;
      }
    }
    __syncthreads();   // one drain per PAIR (4 in the K-loop)

    // issue loads for pair p+1 — in flight under the 32 MFMAs below
    if (p < 3) {
#pragma unroll
      for (int q = 0; q < 2; q++) {
        const float* xr = x + (size_t)((b << 8) + ((p + 1) * 2 + q) * 32 + 2 * dp) * HWw + hw0 + ch * 4;
        va4[q] = *(const float4*)xr;
        vb4[q] = *(const float4*)(xr + HWw);
      }
    }
    // xb_bf stores for pair p — drain at the NEXT pair's barrier
#pragma unroll
    for (int q = 0; q < 2; q++) {
      int s = 2 * p + q;
      int d0r = s * 32 + 2 * dp;
      int fiA = (d0r >> 4) * 64 + q2x * 16 + (d0r & 15);
      size_t base = ((size_t)(b * 128) + spx) * 1024;
      *(float2*)(xb_bf + (base + fiA) * 8 + jx) = *(float2*)paS[q];
      *(float2*)(xb_bf + (base + fiA + 1) * 8 + jx) = *(float2*)pbS[q];
    }
    // MFMA for steps 2p, 2p+1 (1-step-ahead tnbf prefetch)
#pragma unroll
    for (int q = 0; q < 2; q++) {
      int s = 2 * p + q;
      short8 af[4];
#pragma unroll
      for (int mt = 0; mt < 4; mt++) af[mt] = afp[mt];
      if (s < 7) {
        const bf16* tsrc = tnbf + (size_t)(b * 8 + s + 1) * 1024 * 8;
#pragma unroll
        for (int mt = 0; mt < 4; mt++)
          afp[mt] = *(const short8*)(tsrc + (size_t)(((wave << 2) + mt) * 64 + lane) * 8);
      }
      short8 bfv[4];
#pragma unroll
      for (int nt = 0; nt < 4; nt++)
        bfv[nt] = *(const short8*)(bsb + q * 2080 + nt * 520 + lane * 8);
#pragma unroll
      for (int mt = 0; mt < 4; mt++)
#pragma unroll
        for (int nt = 0; nt < 4; nt++) acc[mt][nt] = MFMA16(af[mt], bfv[nt], acc[mt][nt]);
    }
  }

#pragma unroll
  for (int jj = 0; jj < 4; jj++) ssred[(ch * 4 + jj) * 17 + dp] = ssp[jj];
  __syncthreads();
  if (tid < 64) {
    float sum = 0.f;
#pragma unroll
    for (int i = 0; i < 16; i++) sum += ssred[tid * 17 + i];
    nxl[tid] = TEMP_INV / fmaxf(sqrtf(sum), NORM_EPSf);
  }
  __syncthreads();

  float sc[4];
#pragma unroll
  for (int nt = 0; nt < 4; nt++) sc[nt] = nxl[nt * 16 + nl];
#pragma unroll
  for (int mt = 0; mt < 4; mt++)
#pragma unroll
    for (int nt = 0; nt < 4; nt++)
#pragma unroll
      for (int r = 0; r < 4; r++) acc[mt][nt][r] *= sc[nt];

  float* red2 = red + 256;

  float pmax[4];
#pragma unroll
  for (int nt = 0; nt < 4; nt++) {
    float m = acc[0][nt][0];
#pragma unroll
    for (int mt = 0; mt < 4; mt++)
#pragma unroll
      for (int r = 0; r < 4; r++) m = fmaxf(m, acc[mt][nt][r]);
    m = fmaxf(m, __shfl_xor(m, 16, 64));
    m = fmaxf(m, __shfl_xor(m, 32, 64));
    pmax[nt] = m;
  }
  if (lane < 16) {
#pragma unroll
    for (int nt = 0; nt < 4; nt++) red[((wave << 2) + nt) * 16 + nl] = pmax[nt];
  }
  __syncthreads();
  float cmax[4];
#pragma unroll
  for (int nt = 0; nt < 4; nt++) {
    float m = red[nt * 16 + nl];
#pragma unroll
    for (int w2 = 1; w2 < 4; w2++) m = fmaxf(m, red[((w2 << 2) + nt) * 16 + nl]);
    cmax[nt] = m;
  }

  float psum[4];
#pragma unroll
  for (int nt = 0; nt < 4; nt++) {
    float s = 0.f;
#pragma unroll
    for (int mt = 0; mt < 4; mt++)
#pragma unroll
      for (int r = 0; r < 4; r++) {
        float e = __expf(acc[mt][nt][r] - cmax[nt]);
        acc[mt][nt][r] = e;
        s += e;
      }
    s += __shfl_xor(s, 16, 64);
    s += __shfl_xor(s, 32, 64);
    psum[nt] = s;
  }
  if (lane < 16) {
#pragma unroll
    for (int nt = 0; nt < 4; nt++) red2[((wave << 2) + nt) * 16 + nl] = psum[nt];
  }
  __syncthreads();
  float ci[4];
#pragma unroll
  for (int nt = 0; nt < 4; nt++) {
    float s = 0.f;
#pragma unroll
    for (int w2 = 0; w2 < 4; w2++) s += red2[((w2 << 2) + nt) * 16 + nl];
    ci[nt] = 1.0f / s;
  }

  // ---- quantize + spatial sums S (values kept in acc as exact bf16 round-trips) ----
#pragma unroll
  for (int mt = 0; mt < 4; mt++) {
    int slotg = (b << 8) + (wave << 6) + (mt << 4) + (quad << 2);
#pragma unroll
    for (int r = 0; r < 4; r++) {
      float rs = 0.f;
#pragma unroll
      for (int nt = 0; nt < 4; nt++) {
        bf16 hb = f2b(acc[mt][nt][r] * ci[nt] + EPSf);
        float q = b2f(hb);
        acc[mt][nt][r] = q;
        rs += q;
      }
      rs += __shfl_xor(rs, 1, 64);
      rs += __shfl_xor(rs, 2, 64);
      rs += __shfl_xor(rs, 4, 64);
      rs += __shfl_xor(rs, 8, 64);
      if (nl == 0) atomicAdd(&S[slotg + r], rs);
    }
  }

  // ---- attn epilogue: repack through LDS (swizzled), flush with coalesced 16B stores ----
  __syncthreads();                 // red2 reads done; smem reusable
  bf16* rp = (bf16*)smem;          // [1024 frags][8] bf16 = 16 KB (one s' half)
  int jat = nl & 7;
#pragma unroll
  for (int h = 0; h < 2; h++) {    // h = s'-half (nt 0,1 then nt 2,3)
#pragma unroll
    for (int mt = 0; mt < 4; mt++) {
      int fi0 = ((wave << 2) + mt) * 64 + (quad << 2);
#pragma unroll
      for (int ntl = 0; ntl < 2; ntl++) {
        int nt = (h << 1) + ntl;
        int q2p = (ntl << 1) + (nl >> 3);
#pragma unroll
        for (int r = 0; r < 4; r++) {
          int fi = fi0 + q2p * 16 + r;
          int fisw = fi ^ ((fi >> 3) & 3);       // bank-spread swizzle (involution)
          rp[fisw * 8 + jat] = f2b(acc[mt][nt][r]);
        }
      }
    }
    __syncthreads();
    size_t gbase = ((size_t)(b * 128) + (hw0 >> 5) + h) * 1024 * 8;
#pragma unroll
    for (int u = 0; u < 4; u++) {
      int fl = u * 256 + tid;
      int fg = fl ^ ((fl >> 3) & 3);             // inverse (same) swizzle
      short8 vv = *(const short8*)(rp + (size_t)fl * 8);
      *(short8*)(attn_bf + gbase + (size_t)fg * 8) = vv;
    }
    if (h == 0) __syncthreads();   // flush reads done before overwriting rp
  }
}

// ---------------- GEMM2 (MFMA, zero-LDS, full-K, direct t2 write, NO partials) ----------------
// grid 512: b(32) x kp(4) x dgrp(4). b = n&31 -> all 16 blocks/batch on XCD b%8.
__global__ __launch_bounds__(256) void k_gemm2(const bf16* __restrict__ attn_bf,
                                               const bf16* __restrict__ xb_bf,
                                               float* __restrict__ t2) {
  int n = blockIdx.x;
  int b = n & 31;
  int r2 = n >> 5;                 // 0..15
  int kp = r2 & 3;                 // 64-slot tile
  int dgrp = r2 >> 2;              // 64-d tile
  int tid = threadIdx.x;
  int wave = tid >> 6, lane = tid & 63;
  int wr = wave >> 1, wc = wave & 1;

  f32x4 acc[2][2];
#pragma unroll
  for (int i = 0; i < 2; i++)
#pragma unroll
    for (int j = 0; j < 2; j++) acc[i][j] = (f32x4){0.f, 0.f, 0.f, 0.f};

  const bf16* Abase = attn_bf + ((size_t)(b * 128) * 1024 + (size_t)(kp * 4 + wr * 2) * 64) * 8;
  const bf16* Bbase = xb_bf + ((size_t)(b * 128) * 1024 + (size_t)(dgrp * 4 + wc * 2) * 64) * 8;
#pragma unroll 4
  for (int st = 0; st < 128; st++) {
    const bf16* Ap = Abase + (size_t)st * 1024 * 8;
    const bf16* Bp = Bbase + (size_t)st * 1024 * 8;
    short8 a0 = *(const short8*)(Ap + (size_t)lane * 8);
    short8 a1 = *(const short8*)(Ap + (size_t)(64 + lane) * 8);
    short8 b0 = *(const short8*)(Bp + (size_t)lane * 8);
    short8 b1 = *(const short8*)(Bp + (size_t)(64 + lane) * 8);
    acc[0][0] = MFMA16(a0, b0, acc[0][0]);
    acc[0][1] = MFMA16(a0, b1, acc[0][1]);
    acc[1][0] = MFMA16(a1, b0, acc[1][0]);
    acc[1][1] = MFMA16(a1, b1, acc[1][1]);
  }
  int quad = lane >> 4, nl = lane & 15;
#pragma unroll
  for (int i = 0; i < 2; i++)
#pragma unroll
    for (int r = 0; r < 4; r++) {
      int row = (b << 8) + kp * 64 + wr * 32 + i * 16 + quad * 4 + r;
#pragma unroll
      for (int j = 0; j < 2; j++) {
        int col = dgrp * 64 + wc * 32 + j * 16 + nl;
        t2[(size_t)row * Dd + col] = acc[i][j][r];
      }
    }
}

// ---------------- LN_pre: t = LN(t2/S + tgt); also tbf (64-row-group frag order) ----------------
__global__ __launch_bounds__(64) void k_ln_pre(const float* __restrict__ t2,
                                               const float* __restrict__ S,
                                               const float* __restrict__ tgt,
                                               const float* __restrict__ g,
                                               const float* __restrict__ be,
                                               float* __restrict__ t,
                                               bf16* __restrict__ tbf) {
  int row = blockIdx.x;
  int lane = threadIdx.x;
  float sInv = 1.0f / S[row];
  size_t off = (size_t)row * Dd + lane * 4;
  float4 a0 = *(const float4*)(t2 + off);
  const float* pt = tgt + off;
  float v[4];
  v[0] = a0.x * sInv + pt[0];
  v[1] = a0.y * sInv + pt[1];
  v[2] = a0.z * sInv + pt[2];
  v[3] = a0.w * sInv + pt[3];
  float s1 = v[0] + v[1] + v[2] + v[3];
  float s2 = v[0] * v[0] + v[1] * v[1] + v[2] * v[2] + v[3] * v[3];
#pragma unroll
  for (int m = 32; m >= 1; m >>= 1) {
    s1 += __shfl_xor(s1, m, 64);
    s2 += __shfl_xor(s2, m, 64);
  }
  float mu = s1 * (1.0f / 256.0f);
  float var = s2 * (1.0f / 256.0f) - mu * mu;
  float rs = rsqrtf(fmaxf(var, 0.f) + LN_EPSf);
  float* po = t + (size_t)row * Dd + lane * 4;
  bf16 o[4] __attribute__((aligned(8)));
#pragma unroll
  for (int u = 0; u < 4; u++) {
    float val = (v[u] - mu) * rs * g[lane * 4 + u] + be[lane * 4 + u];
    po[u] = val;
    o[u] = f2b(val);
  }
  int s = lane >> 3;
  int q2 = (lane >> 1) & 3;
  int jh = (lane & 1) * 4;
  size_t fi = (size_t)(((row & 63) >> 4) * 64 + q2 * 16 + (row & 15));
  *(float2*)(tbf + ((size_t)((row >> 6) * 8 + s) * 256 + fi) * 8 + jh) = *(float2*)o;
}

// ---------------- FFN GEMM3 (MFMA): h1bf = relu(tbf @ w1bf^T + b1), frag order via LDS repack ----------------
__global__ __launch_bounds__(256) void k_ffn1(const bf16* __restrict__ tbf,
                                              const bf16* __restrict__ w1bf,
                                              const float* __restrict__ b1,
                                              bf16* __restrict__ h1bf) {
  __shared__ __align__(16) bf16 rp[512 * 8];   // 8 KB: 2 frag-sets x 256 frags x 8
  int rowgrp = blockIdx.x >> 5;    // 0..127
  int fgrp = blockIdx.x & 31;      // 0..31
  int tid = threadIdx.x;
  int wave = tid >> 6, lane = tid & 63;
  int am = (wave >> 1) * 2, bn = (wave & 1) * 2;

  f32x4 acc[2][2];
#pragma unroll
  for (int i = 0; i < 2; i++)
#pragma unroll
    for (int j = 0; j < 2; j++) acc[i][j] = (f32x4){0.f, 0.f, 0.f, 0.f};

  const bf16* Abase = tbf + (size_t)rowgrp * 8 * 256 * 8;
  const bf16* Bbase = w1bf + (size_t)fgrp * 8 * 256 * 8;
#pragma unroll
  for (int s = 0; s < 8; s++) {
    short8 af[2], bfr[2];
#pragma unroll
    for (int i = 0; i < 2; i++)
      af[i] = *(const short8*)(Abase + ((size_t)s * 256 + ((am + i) * 64 + lane)) * 8);
#pragma unroll
    for (int j = 0; j < 2; j++)
      bfr[j] = *(const short8*)(Bbase + ((size_t)s * 256 + ((bn + j) * 64 + lane)) * 8);
#pragma unroll
    for (int i = 0; i < 2; i++)
#pragma unroll
      for (int j = 0; j < 2; j++) acc[i][j] = MFMA16(af[i], bfr[j], acc[i][j]);
  }
  int quad = lane >> 4, nl = lane & 15;
  int jat = nl & 7;
#pragma unroll
  for (int j = 0; j < 2; j++) {
    int f = fgrp * 64 + (bn + j) * 16 + nl;
    float bias = b1[f];
    int seth = (bn + j) >> 1;                    // frag-set (32-f half) 0/1
    int q2p = ((bn + j) & 1) * 2 + (nl >> 3);
#pragma unroll
    for (int i = 0; i < 2; i++) {
      int fiBase = (am + i) * 64 + q2p * 16 + (quad << 2);
#pragma unroll
      for (int r = 0; r < 4; r++) {
        float val = fmaxf(acc[i][j][r] + bias, 0.f);
        int fi = fiBase + r;
        int fisw = fi ^ ((fi >> 3) & 3);         // bank-spread swizzle
        rp[(seth * 256 + fisw) * 8 + jat] = f2b(val);
      }
    }
  }
  __syncthreads();
  size_t sp0 = (size_t)(rowgrp * 64) + fgrp * 2;
#pragma unroll
  for (int u = 0; u < 2; u++) {
    int loc = tid;                               // frag within set
    int fg = loc ^ ((loc >> 3) & 3);             // inverse swizzle
    short8 vv = *(const short8*)(rp + ((size_t)u * 256 + loc) * 8);
    *(short8*)(h1bf + ((sp0 + u) * 256 + fg) * 8) = vv;
  }
}

// ---------------- FFN GEMM4 (MFMA, full-K, waves split K, LDS reduce, direct o2 write) ----------------
// grid 512: rowgrp(128) x cg(4). Wave w covers K-steps [w*16, w*16+16); end cross-wave reduce.
__global__ __launch_bounds__(256) void k_ffn2(const bf16* __restrict__ h1bf,
                                              const bf16* __restrict__ w2bf,
                                              float* __restrict__ o2) {
  __shared__ float redsm[4 * 4160];              // 4 waves x (64 rows x 65 pitch) = 66.5 KB
  int n = blockIdx.x;
  int rowgrp = n >> 2;             // 0..127
  int cg = n & 3;                  // 0..3 (64-col group)
  int tid = threadIdx.x;
  int wave = tid >> 6, lane = tid & 63;

  f32x4 acc[4][4];
#pragma unroll
  for (int i = 0; i < 4; i++)
#pragma unroll
    for (int j = 0; j < 4; j++) acc[i][j] = (f32x4){0.f, 0.f, 0.f, 0.f};

#pragma unroll 4
  for (int stl = 0; stl < 16; stl++) {
    int sg = wave * 16 + stl;
    const bf16* Ab = h1bf + ((size_t)(rowgrp * 64 + sg) * 256) * 8;
    const bf16* Bbv = w2bf + ((size_t)(cg * 64 + sg) * 256) * 8;
    short8 af[4], bfr[4];
#pragma unroll
    for (int mt = 0; mt < 4; mt++)
      af[mt] = *(const short8*)(Ab + (size_t)(mt * 64 + lane) * 8);
#pragma unroll
    for (int nt = 0; nt < 4; nt++)
      bfr[nt] = *(const short8*)(Bbv + (size_t)(nt * 64 + lane) * 8);
#pragma unroll
    for (int mt = 0; mt < 4; mt++)
#pragma unroll
      for (int nt = 0; nt < 4; nt++) acc[mt][nt] = MFMA16(af[mt], bfr[nt], acc[mt][nt]);
  }
  int quad = lane >> 4, nl = lane & 15;
  float* my = redsm + wave * 4160;
#pragma unroll
  for (int mt = 0; mt < 4; mt++)
#pragma unroll
    for (int r = 0; r < 4; r++) {
      int row = mt * 16 + quad * 4 + r;
#pragma unroll
      for (int nt = 0; nt < 4; nt++)
        my[row * 65 + nt * 16 + nl] = acc[mt][nt][r];
    }
  __syncthreads();
#pragma unroll
  for (int u = 0; u < 16; u++) {
    int o = u * 256 + tid;
    int row = o >> 6, col = o & 63;
    int li = row * 65 + col;
    float ssum = redsm[li] + redsm[4160 + li] + redsm[8320 + li] + redsm[12480 + li];
    o2[(size_t)(rowgrp * 64 + row) * Dd + cg * 64 + col] = ssum;
  }
}

// ---------------- LN_out: out = LN(o2 + b2 + t) with g3/be3 ----------------
__global__ __launch_bounds__(64) void k_ln_out(const float* __restrict__ o2,
                                               const float* __restrict__ b2v,
                                               const float* __restrict__ t,
                                               const float* __restrict__ g,
                                               const float* __restrict__ be,
                                               float* __restrict__ out) {
  int row = blockIdx.x;
  int lane = threadIdx.x;
  size_t off = (size_t)row * Dd + lane * 4;
  float4 aq = *(const float4*)(o2 + off);
  const float* pt = t + off;
  float v[4];
  v[0] = aq.x + b2v[lane * 4 + 0] + pt[0];
  v[1] = aq.y + b2v[lane * 4 + 1] + pt[1];
  v[2] = aq.z + b2v[lane * 4 + 2] + pt[2];
  v[3] = aq.w + b2v[lane * 4 + 3] + pt[3];
  float s1 = v[0] + v[1] + v[2] + v[3];
  float s2 = v[0] * v[0] + v[1] * v[1] + v[2] * v[2] + v[3] * v[3];
#pragma unroll
  for (int m = 32; m >= 1; m >>= 1) {
    s1 += __shfl_xor(s1, m, 64);
    s2 += __shfl_xor(s2, m, 64);
  }
  float mu = s1 * (1.0f / 256.0f);
  float var = s2 * (1.0f / 256.0f) - mu * mu;
  float rs = rsqrtf(fmaxf(var, 0.f) + LN_EPSf);
  float* pw = out + (size_t)row * Dd + lane * 4;
#pragma unroll
  for (int u = 0; u < 4; u++)
    pw[u] = (v[u] - mu) * rs * g[lane * 4 + u] + be[lane * 4 + u];
}

extern "C" void kernel_launch(void* const* d_in, const int* in_sizes, int n_in,
                              void* d_out, int out_size, void* d_ws, size_t ws_size,
                              hipStream_t stream) {
  const float* x = (const float*)d_in[0];
  const float* tgt = (const float*)d_in[1];
  const float* w1 = (const float*)d_in[2];
  const float* b1 = (const float*)d_in[3];
  const float* w2 = (const float*)d_in[4];
  const float* b2v = (const float*)d_in[5];
  const float* g2 = (const float*)d_in[6];
  const float* be2 = (const float*)d_in[7];
  const float* g3 = (const float*)d_in[8];
  const float* be3 = (const float*)d_in[9];
  float* out = (float*)d_out;

  // Aliasing:
  //   tbf -> tnbf (dead after k_dots)
  //   w1bf/w2bf carved from attn_bf head (attn dead after gemm2; prew runs after gemm2)
  //   t2 (8MB, single) -> h1bf region (h1bf written later by ffn1; t2 read by ln_pre first)
  //   o2 (8MB, single) -> xb_bf region (xb dead after gemm2)
  char* w = (char*)d_ws;
  bf16* tnbf = (bf16*)w;     w += (size_t)Bb * Kk * Dd * 2;   // 4 MB
  float* S = (float*)w;      w += (size_t)Bb * Kk * 4;        // 32 KB
  float* t = (float*)w;      w += (size_t)Bb * Kk * Dd * 4;   // 8 MB
  bf16* attn_bf = (bf16*)w;  w += (size_t)Bb * HWw * Kk * 2;  // 64 MB
  bf16* h1bf = (bf16*)w;     w += (size_t)Bb * Kk * Ff * 2;   // 32 MB
  bf16* xb_bf = (bf16*)w;    w += (size_t)Bb * Dd * HWw * 2;  // 64 MB

  bf16* tbf = tnbf;                        // 4 MB alias
  bf16* w1bf = attn_bf;                    // 1 MB carve
  bf16* w2bf = attn_bf + (size_t)Ff * Dd;  // 1 MB carve
  float* t2 = (float*)h1bf;                // 8 MB alias
  float* o2 = (float*)xb_bf;               // 8 MB alias

  hipMemsetAsync(S, 0, (size_t)Bb * Kk * 4, stream);
  k_tn<<<Bb * Kk, 64, 0, stream>>>(tgt, tnbf);
  k_dots<<<Bb * (HWw / 64), 256, 0, stream>>>(tnbf, x, xb_bf, attn_bf, S);
  k_gemm2<<<512, 256, 0, stream>>>(attn_bf, xb_bf, t2);
  k_prew1<<<Ff, 64, 0, stream>>>(w1, w1bf);
  k_prew2<<<Dd, 64, 0, stream>>>(w2, w2bf);
  k_ln_pre<<<Bb * Kk, 64, 0, stream>>>(t2, S, tgt, g2, be2, t, tbf);
  k_ffn1<<<(Bb * Kk / 64) * (Ff / 64), 256, 0, stream>>>(tbf, w1bf, b1, h1bf);
  k_ffn2<<<512, 256, 0, stream>>>(h1bf, w2bf, o2);
  k_ln_out<<<Bb * Kk, 64, 0, stream>>>(o2, b2v, t, g3, be3, out);
}